// Round 10
// baseline (187.290 us; speedup 1.0000x reference)
//
#include <hip/hip_runtime.h>
#include <hip/hip_bf16.h>
#include <math.h>

#define NPTS   500000
#define NB     256
#define TOPK   10
#define CAP    2048        // per-query candidate cap in k_final
#define SBLK   1024        // sample slices
#define SPER   16          // points per slice -> 16384-pt sample
#define MARGIN 2.0f        // bf16 dot err <~0.5; 4x headroom
#define FPTS   128         // points per k_filter chunk
#define NCHUNK 3907        // ceil(NPTS/128)
#define FBLK   1536        // k_filter grid: 6/CU fully resident; 3 chunks/block
#define LCAP   8           // per-(block,query) local cap; overflow safe-path
#define MS     40          // shorts per LDS row (80 B: 16-B aligned)
#define PMAIN  393216      // main pair region (dwords) < 2^20
#define OCAP   32768       // overflow pair region (dwords)

typedef short v4s  __attribute__((ext_vector_type(4)));
typedef short v8s  __attribute__((ext_vector_type(8)));
typedef float v16f __attribute__((ext_vector_type(16)));

__device__ __forceinline__ unsigned short f2bf(float f) {   // RNE
    unsigned u = __float_as_uint(f);
    unsigned r = u + 0x7FFFu + ((u >> 16) & 1u);
    return (unsigned short)(r >> 16);
}
__device__ __forceinline__ float bf2f(unsigned short h) {
    return __uint_as_float(((unsigned)h) << 16);
}

// --- exact fp32 pieces: bitwise-identical order in k_sample and k_final -----
__device__ __forceinline__ float norm34(const float* __restrict__ r) {
    float a0 = 0.f, a1 = 0.f, a2 = 0.f, a3 = 0.f;
#pragma unroll
    for (int d = 0; d < 32; d += 4) {
        a0 = fmaf(r[d + 0], r[d + 0], a0);
        a1 = fmaf(r[d + 1], r[d + 1], a1);
        a2 = fmaf(r[d + 2], r[d + 2], a2);
        a3 = fmaf(r[d + 3], r[d + 3], a3);
    }
    a0 = fmaf(r[32], r[32], a0);
    a1 = fmaf(r[33], r[33], a1);
    return (a0 + a1) + (a2 + a3);
}
__device__ __forceinline__ float dot34(const float* __restrict__ r, const float* q) {
    float a0 = 0.f, a1 = 0.f, a2 = 0.f, a3 = 0.f;
#pragma unroll
    for (int d = 0; d < 32; d += 4) {
        a0 = fmaf(r[d + 0], q[d + 0], a0);
        a1 = fmaf(r[d + 1], q[d + 1], a1);
        a2 = fmaf(r[d + 2], q[d + 2], a2);
        a3 = fmaf(r[d + 3], q[d + 3], a3);
    }
    a0 = fmaf(r[32], q[32], a0);
    a1 = fmaf(r[33], q[33], a1);
    return (a0 + a1) + (a2 + a3);
}
// float4 LDS variant, IDENTICAL fma order -> bitwise-equal s
__device__ __forceinline__ float dot34_v4(const float4* __restrict__ r4, const float* q) {
    float a0 = 0.f, a1 = 0.f, a2 = 0.f, a3 = 0.f;
#pragma unroll
    for (int dp = 0; dp < 8; ++dp) {
        float4 v = r4[dp];
        a0 = fmaf(v.x, q[4 * dp + 0], a0);
        a1 = fmaf(v.y, q[4 * dp + 1], a1);
        a2 = fmaf(v.z, q[4 * dp + 2], a2);
        a3 = fmaf(v.w, q[4 * dp + 3], a3);
    }
    float2 t = *(const float2*)(r4 + 8);
    a0 = fmaf(t.x, q[32], a0);
    a1 = fmaf(t.y, q[33], a1);
    return (a0 + a1) + (a2 + a3);
}
__device__ __forceinline__ void load_q(const float* __restrict__ obs,
                                       const float* __restrict__ act, int b, float* q) {
#pragma unroll
    for (int d = 0; d < 32; ++d) q[d] = obs[b * 32 + d];
    q[32] = act[b * 2 + 0];
    q[33] = act[b * 2 + 1];
}

// --- kernel 0a: per-(query, 16-pt slice) min of s; minima transposed --------
__global__ __launch_bounds__(256, 4) void k_sample(const float* __restrict__ obs,
                                                   const float* __restrict__ act,
                                                   const float* __restrict__ msa,
                                                   float* __restrict__ minima) {
    __shared__ __align__(16) float sm[SPER * 36];
    __shared__ float smn[SPER];
    const int g = blockIdx.x, t = threadIdx.x;
    const int base = g * SPER;
    for (int i = t; i < SPER * 34; i += 256) {
        int row = i / 34, d = i - row * 34;
        sm[row * 36 + d] = msa[(size_t)base * 34 + i];
    }
    __syncthreads();
    if (t < SPER) smn[t] = norm34(&sm[t * 36]);
    __syncthreads();
    float q[34];
    load_q(obs, act, t, q);
    float best = __builtin_inff();
#pragma unroll
    for (int j = 0; j < SPER; ++j) {
        float s = fmaf(-2.f, dot34_v4((const float4*)&sm[j * 36], q), smn[j]);
        best = fminf(best, s);
    }
    minima[(size_t)t * SBLK + g] = best;          // transposed: k_tau coalesced
}

// --- kernel 0b: tau = 10th-smallest slice-min; pack A-frags; zero cursors ---
__global__ __launch_bounds__(64) void k_tau(const float* __restrict__ minima,
                                            const float* __restrict__ obs,
                                            const float* __restrict__ act,
                                            v8s* __restrict__ afrag,
                                            int* __restrict__ cursor) {
    __shared__ __align__(16) unsigned short qs[48];
    const int b = blockIdx.x, lane = threadIdx.x;
    if (b == 0 && lane == 0) { cursor[0] = 0; cursor[1] = 0; }
    float v[16];
#pragma unroll
    for (int k = 0; k < 16; ++k) v[k] = minima[(size_t)b * SBLK + lane + 64 * k];
    float last = 0.f;
    for (int r = 0; r < TOPK; ++r) {
        float lm = v[0]; int la = 0;
#pragma unroll
        for (int k = 1; k < 16; ++k) { if (v[k] < lm) { lm = v[k]; la = k; } }
        float wm = lm;
        for (int off = 32; off; off >>= 1) wm = fminf(wm, __shfl_xor(wm, off));
        unsigned long long msk = __ballot(lm == wm);
        int first = (int)__builtin_ctzll(msk);
        if (lane == first) {
#pragma unroll
            for (int k = 0; k < 16; ++k) { if (k == la) v[k] = __builtin_inff(); }
        }
        last = wm;   // wave-uniform
    }
    // q-hat = [q(34), -0.5, (tau+MARGIN)/2, 0..0] as bf16 in LDS
    float val = 0.f;
    if (lane < 32)       val = obs[b * 32 + lane];
    else if (lane < 34)  val = act[b * 2 + (lane - 32)];
    else if (lane == 34) val = -0.5f;
    else if (lane == 35) val = 0.5f * (last + MARGIN);
    if (lane < 48) qs[lane] = (lane < 36) ? f2bf(val) : (unsigned short)0;
    __syncthreads();
    // pack A-frags: chunk (s,half) = q-hat shorts [s*16+half*8 .. +8]
    // dest lane-id in a filter wave = half*32 + mrow, query row = qt*32+mrow
    if (lane < 6) {
        int s = lane >> 1, half = lane & 1;
        int qt = b >> 5, mrow = b & 31;
        v8s frag = *(const v8s*)&qs[s * 16 + half * 8];
        afrag[(qt * 3 + s) * 64 + half * 32 + mrow] = frag;
    }
}

// --- kernel 1: MFMA bf16 filter; 2 barriers/chunk; per-lane norm threshold --
__global__ __launch_bounds__(256, 6) void k_filter(const float* __restrict__ msa,
                                                   const v8s* __restrict__ afrag,
                                                   int* __restrict__ cursor,
                                                   unsigned* __restrict__ pbuf,
                                                   int* __restrict__ posq) {
    __shared__ __align__(16) unsigned short lm[FPTS * MS];   // 10240 B bf16 rows
    __shared__ int lcount[NB];                               // 1024 B
    __shared__ int lcand[NB * LCAP];                         // 8192 B
    __shared__ int gbase;
    const int g = blockIdx.x, t = threadIdx.x;
    const int w = t >> 6, lane = t & 63;
    const int mrow = lane & 31, half = lane >> 5;
    lcount[t] = 0;
#pragma unroll 1
    for (int rep = 0; rep < 3; ++rep) {
        const int c = g + rep * FBLK;           // block-uniform chunk id
        if (c >= NCHUNK) break;                 // block-uniform exit
        const int lo = c * FPTS;
        __syncthreads();                        // lm reuse (covers lcount on rep 0)
        // stage: fp32 global (coalesced float2) -> bf16 LDS rows, hw cvt_pk
        for (int i = t; i < FPTS * 17; i += 256) {
            int row = i / 17, dp = i - row * 17;
            int gp = lo + row;
            float2 v = make_float2(0.f, 0.f);
            if (gp < NPTS) v = *(const float2*)&msa[(size_t)gp * 34 + 2 * dp];
            __hip_bfloat162 h2 = __float22bfloat162_rn(v);   // RNE, lo short = v.x
            unsigned pk;
            __builtin_memcpy(&pk, &h2, 4);
            *(unsigned*)&lm[row * MS + 2 * dp] = pk;
        }
        __syncthreads();
        // B frags + per-lane fp32 norm of this lane's point (both halves same)
        const unsigned short* myrow = &lm[(w * 32 + mrow) * MS];
        const int p0 = lo + w * 32 + mrow;
        float n0 = 0.f, n1 = 0.f, n2 = 0.f, n3 = 0.f;
#pragma unroll
        for (int dq = 0; dq < 4; ++dq) {        // shorts 0..31 via b64
            v4s h4 = *(const v4s*)(myrow + 4 * dq);
            float f0 = bf2f((unsigned short)h4[0]);
            float f1 = bf2f((unsigned short)h4[1]);
            float f2 = bf2f((unsigned short)h4[2]);
            float f3 = bf2f((unsigned short)h4[3]);
            n0 = fmaf(f0, f0, n0);
            n1 = fmaf(f1, f1, n1);
            n2 = fmaf(f2, f2, n2);
            n3 = fmaf(f3, f3, n3);
        }
#pragma unroll
        for (int dq = 4; dq < 8; ++dq) {        // shorts 16..31
            v4s h4 = *(const v4s*)(myrow + 4 * dq);
            float f0 = bf2f((unsigned short)h4[0]);
            float f1 = bf2f((unsigned short)h4[1]);
            float f2 = bf2f((unsigned short)h4[2]);
            float f3 = bf2f((unsigned short)h4[3]);
            n0 = fmaf(f0, f0, n0);
            n1 = fmaf(f1, f1, n1);
            n2 = fmaf(f2, f2, n2);
            n3 = fmaf(f3, f3, n3);
        }
        unsigned u33 = *(const unsigned*)(myrow + 32);       // m32,m33 packed
        {
            float f0 = bf2f((unsigned short)(u33 & 0xFFFFu));
            float f1 = bf2f((unsigned short)(u33 >> 16));
            n0 = fmaf(f0, f0, n0);
            n1 = fmaf(f1, f1, n1);
        }
        float thr = 0.5f * ((n0 + n1) + (n2 + n3));          // hit iff acc >= thr
        if (p0 >= NPTS) thr = 1e30f;            // invalid rows never pass
        // B-frags: 2x ds_read_b128 + constructed B2 (proven no-spill pattern)
        const v8s B0 = *(const v8s*)(myrow + half * 8);
        const v8s B1 = *(const v8s*)(myrow + 16 + half * 8);
        v8s B2 = (v8s)(short)0;
        if (half == 0) {
            B2[0] = (short)(unsigned short)(u33 & 0xFFFFu);  // m32 (k=32)
            B2[1] = (short)(unsigned short)(u33 >> 16);      // m33 (k=33)
            B2[3] = (short)0x3F80;              // k=35: 1.0 pairs q's tau-term
        }                                       // k=34 stays 0 (pairs q's -0.5)
#pragma unroll 1
        for (int qt = 0; qt < 8; ++qt) {
            v8s A0 = afrag[(qt * 3 + 0) * 64 + lane];        // L1-hot, coalesced
            v8s A1 = afrag[(qt * 3 + 1) * 64 + lane];
            v8s A2 = afrag[(qt * 3 + 2) * 64 + lane];
            v16f acc;
#pragma unroll
            for (int i = 0; i < 16; ++i) acc[i] = 0.f;
            acc = __builtin_amdgcn_mfma_f32_32x32x16_bf16(A0, B0, acc, 0, 0, 0);
            acc = __builtin_amdgcn_mfma_f32_32x32x16_bf16(A1, B1, acc, 0, 0, 0);
            acc = __builtin_amdgcn_mfma_f32_32x32x16_bf16(A2, B2, acc, 0, 0, 0);
            unsigned hm = 0;
#pragma unroll
            for (int r = 0; r < 16; ++r) hm |= (acc[r] >= thr) ? (1u << r) : 0u;
            while (hm) {                        // rare per lane
                int r = __builtin_ctz(hm);
                hm &= hm - 1;
                int qq = qt * 32 + (r & 3) + 8 * (r >> 2) + 4 * half;
                int slot = atomicAdd(&lcount[qq], 1);
                if (slot < LCAP) lcand[qq * LCAP + slot] = p0;
                else {                          // SAFE overflow: side region
                    int dg = atomicAdd(cursor + 1, 1);
                    if (dg < OCAP) pbuf[PMAIN + dg] = ((unsigned)qq << 19) | (unsigned)p0;
                }
            }
        }
    }
    __syncthreads();
    // flush: prefix-scan -> ONE cursor atomic -> compacted writes + pos table
    int n = lcount[t];
    if (n > LCAP) n = LCAP;
    lcount[t] = n;
    __syncthreads();
    for (int off = 1; off < 256; off <<= 1) {   // Hillis-Steele inclusive scan
        int v = (t >= off) ? lcount[t - off] : 0;
        __syncthreads();
        lcount[t] += v;
        __syncthreads();
    }
    int base_l = lcount[t] - n;
    if (t == 255) gbase = atomicAdd(cursor, lcount[255]);
    __syncthreads();
    int start = gbase + base_l;
    if (start >= PMAIN) { start = 0; n = 0; }
    else if (start + n > PMAIN) n = PMAIN - start;
    posq[g * NB + t] = start | (n << 20);       // coalesced, no atomic
    for (int i = 0; i < n; ++i)
        pbuf[start + i] = (unsigned)lcand[t * LCAP + i];
}

// --- kernel 2: gather my segments, exact fp32 rescore, top-10, softmax ------
__global__ __launch_bounds__(256) void k_final(const float* __restrict__ obs,
                                               const float* __restrict__ act,
                                               const float* __restrict__ msa,
                                               const unsigned* __restrict__ pbuf,
                                               const int* __restrict__ posq,
                                               const int* __restrict__ cursor,
                                               const float* __restrict__ memQ,
                                               float* __restrict__ out) {
    __shared__ float ls[CAP];
    __shared__ int   li[CAP];
    __shared__ int   sc[NB];
    __shared__ int   lcnt;
    __shared__ float rs[4];
    __shared__ int   ri[4];
    __shared__ float sel_s[TOPK];
    __shared__ int   sel_i[TOPK];
    const int b = blockIdx.x, t = threadIdx.x;
    const int lane = t & 63, wid = t >> 6;
    // gather my posq segments (FBLK = 6*256 -> exactly 6 fixed slots)
    int nk[6], pk6[6], tot = 0;
#pragma unroll
    for (int k = 0; k < 6; ++k) {
        int packed = posq[(size_t)(t + 256 * k) * NB + b];
        nk[k] = (packed >> 20) & 0xF;
        pk6[k] = packed & 0xFFFFF;
        tot += nk[k];
    }
    sc[t] = tot;
    __syncthreads();
    for (int off = 1; off < 256; off <<= 1) {   // prefix scan (no atomics)
        int v = (t >= off) ? sc[t - off] : 0;
        __syncthreads();
        sc[t] += v;
        __syncthreads();
    }
    int myoff = sc[t] - tot;
    if (t == 0) lcnt = (sc[255] > CAP) ? CAP : sc[255];
    __syncthreads();
#pragma unroll
    for (int k = 0; k < 6; ++k)
        for (int i = 0; i < nk[k]; ++i) {
            if (myoff < CAP) li[myoff] = (int)pbuf[pk6[k] + i];
            ++myoff;
        }
    // overflow region (normally empty)
    int novf = cursor[1];
    if (novf > OCAP) novf = OCAP;
    for (int j = t; j < novf; j += 256) {
        unsigned pr = pbuf[PMAIN + j];
        if ((int)(pr >> 19) == b) {
            int s = atomicAdd(&lcnt, 1);
            if (s < CAP) li[s] = (int)(pr & 0x7FFFFu);
        }
    }
    __syncthreads();
    int cnt = lcnt;
    if (cnt > CAP) cnt = CAP;
    float q[34];
    load_q(obs, act, b, q);
    for (int j = t; j < cnt; j += 256) {        // exact fp32 re-scores
        const float* row = msa + (size_t)li[j] * 34;
        ls[j] = fmaf(-2.f, dot34(row, q), norm34(row));
    }
    __syncthreads();
    for (int k = 0; k < TOPK; ++k) {
        float bs = __builtin_inff();
        int   bi = 0x7fffffff;
        for (int j = t; j < cnt; j += 256) {
            float s = ls[j]; int i = li[j];
            if (s < bs || (s == bs && i < bi)) { bs = s; bi = i; }
        }
        for (int off = 32; off; off >>= 1) {
            float s2 = __shfl_down(bs, off);
            int   i2 = __shfl_down(bi, off);
            if (s2 < bs || (s2 == bs && i2 < bi)) { bs = s2; bi = i2; }
        }
        if (lane == 0) { rs[wid] = bs; ri[wid] = bi; }
        __syncthreads();
        if (t == 0) {
            float fs = rs[0]; int fi = ri[0];
#pragma unroll
            for (int ww = 1; ww < 4; ++ww) {
                if (rs[ww] < fs || (rs[ww] == fs && ri[ww] < fi)) { fs = rs[ww]; fi = ri[ww]; }
            }
            sel_s[k] = fs; sel_i[k] = fi;
        }
        __syncthreads();
        const int win = sel_i[k];
        for (int j = t; j < cnt; j += 256) {
            if (li[j] == win) ls[j] = __builtin_inff();
        }
        __syncthreads();
    }
    if (t == 0) {
        float m = sel_s[TOPK - 1];
        float wsum = 0.f, acc = 0.f;
#pragma unroll
        for (int k = 0; k < TOPK; ++k) {
            if (sel_i[k] == 0x7fffffff) continue;
            float w2 = expf(sel_s[k] - m);
            wsum += w2;
            acc = fmaf(w2, memQ[sel_i[k]], acc);
        }
        out[b] = acc / wsum;
    }
}

extern "C" void kernel_launch(void* const* d_in, const int* in_sizes, int n_in,
                              void* d_out, int out_size, void* d_ws, size_t ws_size,
                              hipStream_t stream) {
    const float* obs = (const float*)d_in[0];   // [256,32]
    const float* act = (const float*)d_in[1];   // [256,2]
    const float* msa = (const float*)d_in[2];   // [500000,34]
    const float* mq  = (const float*)d_in[3];   // [500000,1]
    float* out = (float*)d_out;                 // [256]

    char* ws = (char*)d_ws;
    int*      cursor = (int*)ws;                            // 8 B
    v8s*      afrag  = (v8s*)(ws + 256);                    // 24576 B
    float*    minima = (float*)(ws + 32768);                // 1 MB (256 x 1024)
    int*      posq   = (int*)(ws + 32768 + 1048576);        // 1572864 B (1536 x 256)
    unsigned* pbuf   = (unsigned*)(ws + 32768 + 1048576 + 1572864); // 1703936 B
    // total ws use ~4.3 MB

    k_sample<<<SBLK, 256, 0, stream>>>(obs, act, msa, minima);
    k_tau   <<<NB, 64, 0, stream>>>(minima, obs, act, afrag, cursor);
    k_filter<<<FBLK, 256, 0, stream>>>(msa, afrag, cursor, pbuf, posq);
    k_final <<<NB, 256, 0, stream>>>(obs, act, msa, pbuf, posq, cursor, mq, out);
}

// Round 11
// 182.330 us; speedup vs baseline: 1.0272x; 1.0272x over previous
//
#include <hip/hip_runtime.h>
#include <hip/hip_bf16.h>
#include <math.h>

#define NPTS   500000
#define NB     256
#define TOPK   10
#define CAP    2048        // per-query candidate cap in k_final
#define SBLK   1024        // sample slices
#define SPER   16          // points per slice -> 16384-pt sample
#define MARGIN 2.0f        // bf16 dot err <~0.5; 4x headroom
#define NWCH   15625       // 500000 / 32: wave-chunks of 32 points (exact!)
#define FBLK   1536        // k_filter grid: 6 blocks/CU fully resident
#define LCAP   8           // per-(block,query) local cap; overflow safe-path
#define PMAIN  393216      // main pair region (dwords) < 2^20
#define OCAP   32768       // overflow pair region (dwords)

typedef short v2s  __attribute__((ext_vector_type(2)));
typedef short v4s  __attribute__((ext_vector_type(4)));
typedef short v8s  __attribute__((ext_vector_type(8)));
typedef float v16f __attribute__((ext_vector_type(16)));

__device__ __forceinline__ unsigned short f2bf(float f) {   // RNE
    unsigned u = __float_as_uint(f);
    unsigned r = u + 0x7FFFu + ((u >> 16) & 1u);
    return (unsigned short)(r >> 16);
}
__device__ __forceinline__ float bf2f(unsigned short h) {
    return __uint_as_float(((unsigned)h) << 16);
}
// packed f32x2 -> bf16x2 (hw cvt, RNE; lo short = f.x). memcpy-pun: legal & proven.
__device__ __forceinline__ v2s pk2(float2 f) {
    __hip_bfloat162 h = __float22bfloat162_rn(f);
    v2s r;
    __builtin_memcpy(&r, &h, 4);
    return r;
}

// --- exact fp32 pieces: bitwise-identical order in k_sample and k_final -----
__device__ __forceinline__ float norm34(const float* __restrict__ r) {
    float a0 = 0.f, a1 = 0.f, a2 = 0.f, a3 = 0.f;
#pragma unroll
    for (int d = 0; d < 32; d += 4) {
        a0 = fmaf(r[d + 0], r[d + 0], a0);
        a1 = fmaf(r[d + 1], r[d + 1], a1);
        a2 = fmaf(r[d + 2], r[d + 2], a2);
        a3 = fmaf(r[d + 3], r[d + 3], a3);
    }
    a0 = fmaf(r[32], r[32], a0);
    a1 = fmaf(r[33], r[33], a1);
    return (a0 + a1) + (a2 + a3);
}
__device__ __forceinline__ float dot34(const float* __restrict__ r, const float* q) {
    float a0 = 0.f, a1 = 0.f, a2 = 0.f, a3 = 0.f;
#pragma unroll
    for (int d = 0; d < 32; d += 4) {
        a0 = fmaf(r[d + 0], q[d + 0], a0);
        a1 = fmaf(r[d + 1], q[d + 1], a1);
        a2 = fmaf(r[d + 2], q[d + 2], a2);
        a3 = fmaf(r[d + 3], q[d + 3], a3);
    }
    a0 = fmaf(r[32], q[32], a0);
    a1 = fmaf(r[33], q[33], a1);
    return (a0 + a1) + (a2 + a3);
}
// float4 LDS variant, IDENTICAL fma order -> bitwise-equal s
__device__ __forceinline__ float dot34_v4(const float4* __restrict__ r4, const float* q) {
    float a0 = 0.f, a1 = 0.f, a2 = 0.f, a3 = 0.f;
#pragma unroll
    for (int dp = 0; dp < 8; ++dp) {
        float4 v = r4[dp];
        a0 = fmaf(v.x, q[4 * dp + 0], a0);
        a1 = fmaf(v.y, q[4 * dp + 1], a1);
        a2 = fmaf(v.z, q[4 * dp + 2], a2);
        a3 = fmaf(v.w, q[4 * dp + 3], a3);
    }
    float2 t = *(const float2*)(r4 + 8);
    a0 = fmaf(t.x, q[32], a0);
    a1 = fmaf(t.y, q[33], a1);
    return (a0 + a1) + (a2 + a3);
}
__device__ __forceinline__ void load_q(const float* __restrict__ obs,
                                       const float* __restrict__ act, int b, float* q) {
#pragma unroll
    for (int d = 0; d < 32; ++d) q[d] = obs[b * 32 + d];
    q[32] = act[b * 2 + 0];
    q[33] = act[b * 2 + 1];
}

// --- kernel 0a: per-(query, 16-pt slice) min of s; minima transposed --------
__global__ __launch_bounds__(256, 4) void k_sample(const float* __restrict__ obs,
                                                   const float* __restrict__ act,
                                                   const float* __restrict__ msa,
                                                   float* __restrict__ minima) {
    __shared__ __align__(16) float sm[SPER * 36];
    __shared__ float smn[SPER];
    const int g = blockIdx.x, t = threadIdx.x;
    const int base = g * SPER;
    for (int i = t; i < SPER * 34; i += 256) {
        int row = i / 34, d = i - row * 34;
        sm[row * 36 + d] = msa[(size_t)base * 34 + i];
    }
    __syncthreads();
    if (t < SPER) smn[t] = norm34(&sm[t * 36]);
    __syncthreads();
    float q[34];
    load_q(obs, act, t, q);
    float best = __builtin_inff();
#pragma unroll
    for (int j = 0; j < SPER; ++j) {
        float s = fmaf(-2.f, dot34_v4((const float4*)&sm[j * 36], q), smn[j]);
        best = fminf(best, s);
    }
    minima[(size_t)t * SBLK + g] = best;          // transposed: k_tau coalesced
}

// --- kernel 0b: tau = 10th-smallest slice-min; pack A-frags; zero cursors ---
__global__ __launch_bounds__(64) void k_tau(const float* __restrict__ minima,
                                            const float* __restrict__ obs,
                                            const float* __restrict__ act,
                                            v8s* __restrict__ afrag,
                                            int* __restrict__ cursor) {
    __shared__ __align__(16) unsigned short qs[48];
    const int b = blockIdx.x, lane = threadIdx.x;
    if (b == 0 && lane == 0) { cursor[0] = 0; cursor[1] = 0; }
    float v[16];
#pragma unroll
    for (int k = 0; k < 16; ++k) v[k] = minima[(size_t)b * SBLK + lane + 64 * k];
    float last = 0.f;
    for (int r = 0; r < TOPK; ++r) {
        float lm = v[0]; int la = 0;
#pragma unroll
        for (int k = 1; k < 16; ++k) { if (v[k] < lm) { lm = v[k]; la = k; } }
        float wm = lm;
        for (int off = 32; off; off >>= 1) wm = fminf(wm, __shfl_xor(wm, off));
        unsigned long long msk = __ballot(lm == wm);
        int first = (int)__builtin_ctzll(msk);
        if (lane == first) {
#pragma unroll
            for (int k = 0; k < 16; ++k) { if (k == la) v[k] = __builtin_inff(); }
        }
        last = wm;   // wave-uniform
    }
    // q-hat = [q(34), -0.5, (tau+MARGIN)/2, 0..0] as bf16 in LDS
    float val = 0.f;
    if (lane < 32)       val = obs[b * 32 + lane];
    else if (lane < 34)  val = act[b * 2 + (lane - 32)];
    else if (lane == 34) val = -0.5f;
    else if (lane == 35) val = 0.5f * (last + MARGIN);
    if (lane < 48) qs[lane] = (lane < 36) ? f2bf(val) : (unsigned short)0;
    __syncthreads();
    // pack A-frags: chunk (s,half) = q-hat shorts [s*16+half*8 .. +8]
    // dest lane-id in a filter wave = half*32 + mrow, query row = qt*32+mrow
    if (lane < 6) {
        int s = lane >> 1, half = lane & 1;
        int qt = b >> 5, mrow = b & 31;
        v8s frag = *(const v8s*)&qs[s * 16 + half * 8];
        afrag[(qt * 3 + s) * 64 + half * 32 + mrow] = frag;
    }
}

// --- kernel 1: MFMA bf16 filter; BARRIER-FREE main loop, direct-global B ----
__global__ __launch_bounds__(256, 6) void k_filter(const float* __restrict__ msa,
                                                   const v8s* __restrict__ afrag,
                                                   int* __restrict__ cursor,
                                                   unsigned* __restrict__ pbuf,
                                                   int* __restrict__ posq) {
    __shared__ int lcount[NB];                               // 1024 B
    __shared__ int lcand[NB * LCAP];                         // 8192 B
    __shared__ int gbase;
    const int g = blockIdx.x, t = threadIdx.x;
    const int w = t >> 6, lane = t & 63;
    const int mrow = lane & 31, half = lane >> 5;
    lcount[t] = 0;
    __syncthreads();
    const int gw = g * 4 + w;                   // global wave id
#pragma unroll 1
    for (int wc = gw; wc < NWCH; wc += FBLK * 4) {   // wave-private chunk stream
        const int p0 = wc * 32 + mrow;          // always < NPTS (exact tiling)
        const float* rp = msa + (size_t)p0 * 34;
        // this lane's 16 K-dims (half-split) + dims 32,33 — all 8-B aligned
        float2 e0 = *(const float2*)(rp + half * 8 + 0);
        float2 e1 = *(const float2*)(rp + half * 8 + 2);
        float2 e2 = *(const float2*)(rp + half * 8 + 4);
        float2 e3 = *(const float2*)(rp + half * 8 + 6);
        float2 e4 = *(const float2*)(rp + 16 + half * 8 + 0);
        float2 e5 = *(const float2*)(rp + 16 + half * 8 + 2);
        float2 e6 = *(const float2*)(rp + 16 + half * 8 + 4);
        float2 e7 = *(const float2*)(rp + 16 + half * 8 + 6);
        float2 e8 = *(const float2*)(rp + 32);
        // per-lane partial fp32 norm; lane pair (half0,half1) shares the row
        float n0 = 0.f, n1 = 0.f;
        n0 = fmaf(e0.x, e0.x, n0); n1 = fmaf(e0.y, e0.y, n1);
        n0 = fmaf(e1.x, e1.x, n0); n1 = fmaf(e1.y, e1.y, n1);
        n0 = fmaf(e2.x, e2.x, n0); n1 = fmaf(e2.y, e2.y, n1);
        n0 = fmaf(e3.x, e3.x, n0); n1 = fmaf(e3.y, e3.y, n1);
        n0 = fmaf(e4.x, e4.x, n0); n1 = fmaf(e4.y, e4.y, n1);
        n0 = fmaf(e5.x, e5.x, n0); n1 = fmaf(e5.y, e5.y, n1);
        n0 = fmaf(e6.x, e6.x, n0); n1 = fmaf(e6.y, e6.y, n1);
        n0 = fmaf(e7.x, e7.x, n0); n1 = fmaf(e7.y, e7.y, n1);
        float part = n0 + n1;
        part = fmaf(e8.x, e8.x * 0.5f, part);   // half of dims 32/33 per lane
        part = fmaf(e8.y, e8.y * 0.5f, part);
        float nrm = part + __shfl_xor(part, 32);
        float thr = 0.5f * nrm;                 // hit iff acc >= thr
        // B-frags: shufflevector-of-pk2 (proven no-spill) + literal-index B2
        v4s b0lo = __builtin_shufflevector(pk2(e0), pk2(e1), 0, 1, 2, 3);
        v4s b0hi = __builtin_shufflevector(pk2(e2), pk2(e3), 0, 1, 2, 3);
        v8s B0 = __builtin_shufflevector(b0lo, b0hi, 0, 1, 2, 3, 4, 5, 6, 7);
        v4s b1lo = __builtin_shufflevector(pk2(e4), pk2(e5), 0, 1, 2, 3);
        v4s b1hi = __builtin_shufflevector(pk2(e6), pk2(e7), 0, 1, 2, 3);
        v8s B1 = __builtin_shufflevector(b1lo, b1hi, 0, 1, 2, 3, 4, 5, 6, 7);
        v8s B2 = (v8s)(short)0;
        if (half == 0) {
            v2s m33 = pk2(e8);
            B2[0] = m33[0];                     // m32 (k=32)
            B2[1] = m33[1];                     // m33 (k=33)
            B2[3] = (short)0x3F80;              // k=35: 1.0 pairs q's tau-term
        }                                       // k=34 stays 0 (pairs q's -0.5)
#pragma unroll 1
        for (int qt = 0; qt < 8; ++qt) {
            v8s A0 = afrag[(qt * 3 + 0) * 64 + lane];        // L1-hot, coalesced
            v8s A1 = afrag[(qt * 3 + 1) * 64 + lane];
            v8s A2 = afrag[(qt * 3 + 2) * 64 + lane];
            v16f acc;
#pragma unroll
            for (int i = 0; i < 16; ++i) acc[i] = 0.f;
            acc = __builtin_amdgcn_mfma_f32_32x32x16_bf16(A0, B0, acc, 0, 0, 0);
            acc = __builtin_amdgcn_mfma_f32_32x32x16_bf16(A1, B1, acc, 0, 0, 0);
            acc = __builtin_amdgcn_mfma_f32_32x32x16_bf16(A2, B2, acc, 0, 0, 0);
            unsigned hm = 0;
#pragma unroll
            for (int r = 0; r < 16; ++r) hm |= (acc[r] >= thr) ? (1u << r) : 0u;
            while (hm) {                        // rare per lane
                int r = __builtin_ctz(hm);
                hm &= hm - 1;
                int qq = qt * 32 + (r & 3) + 8 * (r >> 2) + 4 * half;
                int slot = atomicAdd(&lcount[qq], 1);
                if (slot < LCAP) lcand[qq * LCAP + slot] = p0;
                else {                          // SAFE overflow: side region
                    int dg = atomicAdd(cursor + 1, 1);
                    if (dg < OCAP) pbuf[PMAIN + dg] = ((unsigned)qq << 19) | (unsigned)p0;
                }
            }
        }
    }
    __syncthreads();
    // flush: prefix-scan -> ONE cursor atomic -> compacted writes + pos table
    int n = lcount[t];
    if (n > LCAP) n = LCAP;
    lcount[t] = n;
    __syncthreads();
    for (int off = 1; off < 256; off <<= 1) {   // Hillis-Steele inclusive scan
        int v = (t >= off) ? lcount[t - off] : 0;
        __syncthreads();
        lcount[t] += v;
        __syncthreads();
    }
    int base_l = lcount[t] - n;
    if (t == 255) gbase = atomicAdd(cursor, lcount[255]);
    __syncthreads();
    int start = gbase + base_l;
    if (start >= PMAIN) { start = 0; n = 0; }
    else if (start + n > PMAIN) n = PMAIN - start;
    posq[g * NB + t] = start | (n << 20);       // coalesced, no atomic
    for (int i = 0; i < n; ++i)
        pbuf[start + i] = (unsigned)lcand[t * LCAP + i];
}

// --- kernel 2: gather my segments, exact fp32 rescore, top-10, softmax ------
__global__ __launch_bounds__(256) void k_final(const float* __restrict__ obs,
                                               const float* __restrict__ act,
                                               const float* __restrict__ msa,
                                               const unsigned* __restrict__ pbuf,
                                               const int* __restrict__ posq,
                                               const int* __restrict__ cursor,
                                               const float* __restrict__ memQ,
                                               float* __restrict__ out) {
    __shared__ float ls[CAP];
    __shared__ int   li[CAP];
    __shared__ int   sc[NB];
    __shared__ int   lcnt;
    __shared__ float rs[4];
    __shared__ int   ri[4];
    __shared__ float sel_s[TOPK];
    __shared__ int   sel_i[TOPK];
    const int b = blockIdx.x, t = threadIdx.x;
    const int lane = t & 63, wid = t >> 6;
    // gather my posq segments (FBLK = 6*256 -> exactly 6 fixed slots)
    int nk[6], pk6[6], tot = 0;
#pragma unroll
    for (int k = 0; k < 6; ++k) {
        int packed = posq[(size_t)(t + 256 * k) * NB + b];
        nk[k] = (packed >> 20) & 0xF;
        pk6[k] = packed & 0xFFFFF;
        tot += nk[k];
    }
    sc[t] = tot;
    __syncthreads();
    for (int off = 1; off < 256; off <<= 1) {   // prefix scan (no atomics)
        int v = (t >= off) ? sc[t - off] : 0;
        __syncthreads();
        sc[t] += v;
        __syncthreads();
    }
    int myoff = sc[t] - tot;
    if (t == 0) lcnt = (sc[255] > CAP) ? CAP : sc[255];
    __syncthreads();
#pragma unroll
    for (int k = 0; k < 6; ++k)
        for (int i = 0; i < nk[k]; ++i) {
            if (myoff < CAP) li[myoff] = (int)pbuf[pk6[k] + i];
            ++myoff;
        }
    // overflow region (normally empty)
    int novf = cursor[1];
    if (novf > OCAP) novf = OCAP;
    for (int j = t; j < novf; j += 256) {
        unsigned pr = pbuf[PMAIN + j];
        if ((int)(pr >> 19) == b) {
            int s = atomicAdd(&lcnt, 1);
            if (s < CAP) li[s] = (int)(pr & 0x7FFFFu);
        }
    }
    __syncthreads();
    int cnt = lcnt;
    if (cnt > CAP) cnt = CAP;
    float q[34];
    load_q(obs, act, b, q);
    for (int j = t; j < cnt; j += 256) {        // exact fp32 re-scores
        const float* row = msa + (size_t)li[j] * 34;
        ls[j] = fmaf(-2.f, dot34(row, q), norm34(row));
    }
    __syncthreads();
    for (int k = 0; k < TOPK; ++k) {
        float bs = __builtin_inff();
        int   bi = 0x7fffffff;
        for (int j = t; j < cnt; j += 256) {
            float s = ls[j]; int i = li[j];
            if (s < bs || (s == bs && i < bi)) { bs = s; bi = i; }
        }
        for (int off = 32; off; off >>= 1) {
            float s2 = __shfl_down(bs, off);
            int   i2 = __shfl_down(bi, off);
            if (s2 < bs || (s2 == bs && i2 < bi)) { bs = s2; bi = i2; }
        }
        if (lane == 0) { rs[wid] = bs; ri[wid] = bi; }
        __syncthreads();
        if (t == 0) {
            float fs = rs[0]; int fi = ri[0];
#pragma unroll
            for (int ww = 1; ww < 4; ++ww) {
                if (rs[ww] < fs || (rs[ww] == fs && ri[ww] < fi)) { fs = rs[ww]; fi = ri[ww]; }
            }
            sel_s[k] = fs; sel_i[k] = fi;
        }
        __syncthreads();
        const int win = sel_i[k];
        for (int j = t; j < cnt; j += 256) {
            if (li[j] == win) ls[j] = __builtin_inff();
        }
        __syncthreads();
    }
    if (t == 0) {
        float m = sel_s[TOPK - 1];
        float wsum = 0.f, acc = 0.f;
#pragma unroll
        for (int k = 0; k < TOPK; ++k) {
            if (sel_i[k] == 0x7fffffff) continue;
            float w2 = expf(sel_s[k] - m);
            wsum += w2;
            acc = fmaf(w2, memQ[sel_i[k]], acc);
        }
        out[b] = acc / wsum;
    }
}

extern "C" void kernel_launch(void* const* d_in, const int* in_sizes, int n_in,
                              void* d_out, int out_size, void* d_ws, size_t ws_size,
                              hipStream_t stream) {
    const float* obs = (const float*)d_in[0];   // [256,32]
    const float* act = (const float*)d_in[1];   // [256,2]
    const float* msa = (const float*)d_in[2];   // [500000,34]
    const float* mq  = (const float*)d_in[3];   // [500000,1]
    float* out = (float*)d_out;                 // [256]

    char* ws = (char*)d_ws;
    int*      cursor = (int*)ws;                            // 8 B
    v8s*      afrag  = (v8s*)(ws + 256);                    // 24576 B
    float*    minima = (float*)(ws + 32768);                // 1 MB (256 x 1024)
    int*      posq   = (int*)(ws + 32768 + 1048576);        // 1572864 B (1536 x 256)
    unsigned* pbuf   = (unsigned*)(ws + 32768 + 1048576 + 1572864); // 1703936 B
    // total ws use ~4.3 MB

    k_sample<<<SBLK, 256, 0, stream>>>(obs, act, msa, minima);
    k_tau   <<<NB, 64, 0, stream>>>(minima, obs, act, afrag, cursor);
    k_filter<<<FBLK, 256, 0, stream>>>(msa, afrag, cursor, pbuf, posq);
    k_final <<<NB, 256, 0, stream>>>(obs, act, msa, pbuf, posq, cursor, mq, out);
}